// Round 4
// baseline (187.202 us; speedup 1.0000x reference)
//
#include <hip/hip_runtime.h>
#include <hip/hip_bf16.h>

#define E_TOT 200000
#define NZ 64
#define ATTR_D 768
#define KD 832          // 64 + 768
#define HID_D 128
#define NCLS 5
#define NAT 24          // attr K-steps of 32 floats (kt = 2..25)

typedef __attribute__((ext_vector_type(8))) short short8;   // 8 bf16 (4 VGPRs)
typedef __attribute__((ext_vector_type(4))) float f32x4;    // MFMA accumulator

typedef __attribute__((address_space(3))) unsigned       lds_u32_t;
typedef const __attribute__((address_space(1))) unsigned glob_u32_t;

__device__ __forceinline__ unsigned pk2(float a, float b) {
    __hip_bfloat162 h = __float22bfloat162_rn(make_float2(a, b));
    return *reinterpret_cast<unsigned*>(&h);
}

__device__ __forceinline__ short8 pack8(const float4 x0, const float4 x1) {
    union { unsigned u[4]; short8 s; } r;
    r.u[0] = pk2(x0.x, x0.y);
    r.u[1] = pk2(x0.z, x0.w);
    r.u[2] = pk2(x1.x, x1.y);
    r.u[3] = pk2(x1.z, x1.w);
    return r.s;
}

// ---- prep: W1 [832][128] f32 -> frag-ordered bf16 w1f[kt][f][lane][8]
// value = W1t[n = f*16 + (lane&15)][k = kt*32 + (lane>>4)*8 + j]
__global__ void prep_w1f(const float* __restrict__ W1, __hip_bfloat16* __restrict__ w1f) {
    int idx = blockIdx.x * 256 + threadIdx.x;       // over 26*8*64*8 = 106496
    if (idx >= 26 * 8 * 64 * 8) return;
    int j    = idx & 7;
    int lane = (idx >> 3) & 63;
    int f    = (idx >> 9) & 7;
    int kt   = idx >> 12;
    int n = f * 16 + (lane & 15);
    int k = kt * 32 + (lane >> 4) * 8 + j;
    w1f[idx] = __float2bfloat16(W1[(size_t)k * HID_D + n]);
}

// ---- main: barrier-FREE wave-local pipeline. 4 waves x 32 edge rows = 128 edges/block.
// Each wave stages ITS OWN 4KB slice of each attr tile (3-deep LDS ring) via
// global_load_lds; sync is per-wave counted s_waitcnt vmcnt(12) — no __syncthreads.
// B (W1 frags, L2-resident) register-double-buffered, issued before the next stage
// so in-order vmcnt retirement never drains a future stage early.
__global__ __launch_bounds__(256, 2) void gcn_main(
    const float* __restrict__ z, const int* __restrict__ ei,
    const float* __restrict__ attr, const __hip_bfloat16* __restrict__ w1f,
    const float* __restrict__ b1, const float* __restrict__ W2,
    const float* __restrict__ b2, float* __restrict__ out) {

    __shared__ float As[3][128 * 32];   // 3 x 16 KB ring

    const int t    = threadIdx.x;
    const int wv   = t >> 6;
    const int lane = t & 63;
    const int g    = lane >> 4;     // k-group
    const int c0   = lane & 15;
    const int e0   = blockIdx.x * 128;

    // ---- staging sources: wave-local slice. Lane covers linear LDS byte
    // L = wv*4096 + i*1024 + lane*16; LDS stays linear, chunk XOR swizzle applied
    // to the GLOBAL source address (rule: both-sides-or-neither).
    const float* sbase[4];
#pragma unroll
    for (int i = 0; i < 4; ++i) {
        int L   = wv * 4096 + i * 1024 + lane * 16;
        int row = L >> 7;                 // 128B per row -> rows wv*32..wv*32+31
        int p   = (L >> 4) & 7;           // physical 16B chunk slot
        int c   = p ^ (row & 7);          // logical chunk stored there
        int er  = e0 + row; if (er >= E_TOT) er = E_TOT - 1;
        sbase[i] = attr + (size_t)er * ATTR_D + c * 4;
    }

    auto STAGE = [&](int buf, int s) {
#pragma unroll
        for (int i = 0; i < 4; ++i) {
            __builtin_amdgcn_global_load_lds(
                (glob_u32_t*)(sbase[i] + s * 32),
                (lds_u32_t*)&As[buf][wv * 1024 + i * 256],
                16, 0, 0);
        }
    };

    const __hip_bfloat16* wf = w1f + (size_t)lane * 8;
    auto LOADB = [&](int kt, short8(&b)[8]) {
#pragma unroll
        for (int f = 0; f < 8; ++f)
            b[f] = *reinterpret_cast<const short8*>(wf + (size_t)(kt * 8 + f) * 512);
    };

    // ---- edge indices (issue before stages; their drain is prologue-only)
    const float* zsp[2];
    const float* zdp[2];
#pragma unroll
    for (int m = 0; m < 2; ++m) {
        int e = e0 + wv * 32 + m * 16 + c0; if (e >= E_TOT) e = E_TOT - 1;
        int si = ei[e];
        int di = ei[E_TOT + e];
        zsp[m] = z + (size_t)si * NZ + g * 8;
        zdp[m] = z + (size_t)di * NZ + g * 8;
    }

    f32x4 acc[2][8];
#pragma unroll
    for (int m = 0; m < 2; ++m)
#pragma unroll
        for (int f = 0; f < 8; ++f) acc[m][f] = (f32x4){0.f, 0.f, 0.f, 0.f};

    // ---- prologue: start the attr stream ASAP, then do the z-phase under it
    short8 bX[8], bY[8];
    STAGE(0, 0);
    LOADB(2, bX);
    STAGE(1, 1);

    {
        short8 bz0[8], bz1[8];
        LOADB(0, bz0);
        LOADB(1, bz1);
#pragma unroll
        for (int kt = 0; kt < 2; ++kt) {
            short8 a[2];
#pragma unroll
            for (int m = 0; m < 2; ++m) {
                const float4* ps = reinterpret_cast<const float4*>(zsp[m] + kt * 32);
                const float4* pd = reinterpret_cast<const float4*>(zdp[m] + kt * 32);
                float4 s0 = ps[0], s1 = ps[1];
                float4 d0 = pd[0], d1 = pd[1];
                float4 x0 = make_float4(s0.x * d0.x, s0.y * d0.y, s0.z * d0.z, s0.w * d0.w);
                float4 x1 = make_float4(s1.x * d1.x, s1.y * d1.y, s1.z * d1.z, s1.w * d1.w);
                a[m] = pack8(x0, x1);
            }
#pragma unroll
            for (int f = 0; f < 8; ++f) {
                short8 bb = kt ? bz1[f] : bz0[f];
                acc[0][f] = __builtin_amdgcn_mfma_f32_16x16x32_bf16(a[0], bb, acc[0][f], 0, 0, 0);
                acc[1][f] = __builtin_amdgcn_mfma_f32_16x16x32_bf16(a[1], bb, acc[1][f], 0, 0, 0);
            }
        }
    }

    // ---- main pipeline: iter at consumes stage at (kt=at+2) from buf at%3.
    // Issue order per iter: [wait vmcnt(12)] ds_read, LOADB(at+1's B), STAGE(at+2), MFMA.
    // Invariant: ops newer than S(at) are exactly B(at)(8)+S(at+1)(4)=12 -> vmcnt(12)
    // proves S(at) landed while S(at+1) stays in flight. Unroll x6 so buf indices and
    // B register sets are compile-time.
#define STEP(AT, BUF, BCUR, BNXT)                                              \
    {                                                                          \
        asm volatile("s_waitcnt vmcnt(12)" ::: "memory");                      \
        __builtin_amdgcn_sched_barrier(0);                                     \
        const float* Ab = &As[BUF][0];                                         \
        int r0  = wv * 32 + c0;                                                \
        int r1  = r0 + 16;                                                     \
        int p00 = ((g * 2)     ^ (r0 & 7)) * 4;                                \
        int p01 = ((g * 2 + 1) ^ (r0 & 7)) * 4;                                \
        int p10 = ((g * 2)     ^ (r1 & 7)) * 4;                                \
        int p11 = ((g * 2 + 1) ^ (r1 & 7)) * 4;                                \
        float4 x00 = *reinterpret_cast<const float4*>(Ab + r0 * 32 + p00);     \
        float4 x01 = *reinterpret_cast<const float4*>(Ab + r0 * 32 + p01);     \
        float4 x10 = *reinterpret_cast<const float4*>(Ab + r1 * 32 + p10);     \
        float4 x11 = *reinterpret_cast<const float4*>(Ab + r1 * 32 + p11);     \
        LOADB(((AT) + 3 > 25 ? 25 : (AT) + 3), BNXT);                          \
        STAGE(((AT) + 2) % 3, ((AT) + 2 > 23 ? 23 : (AT) + 2));                \
        short8 a0 = pack8(x00, x01);                                           \
        short8 a1 = pack8(x10, x11);                                           \
        _Pragma("unroll")                                                      \
        for (int f = 0; f < 8; ++f) {                                          \
            acc[0][f] = __builtin_amdgcn_mfma_f32_16x16x32_bf16(a0, BCUR[f], acc[0][f], 0, 0, 0); \
            acc[1][f] = __builtin_amdgcn_mfma_f32_16x16x32_bf16(a1, BCUR[f], acc[1][f], 0, 0, 0); \
        }                                                                      \
    }

    for (int at = 0; at < NAT; at += 6) {   // at in {0,6,12,18}, all ≡ 0 (mod 3)
        STEP(at + 0, 0, bX, bY)
        STEP(at + 1, 1, bY, bX)
        STEP(at + 2, 2, bX, bY)
        STEP(at + 3, 0, bY, bX)
        STEP(at + 4, 1, bX, bY)
        STEP(at + 5, 2, bY, bX)
    }
#undef STEP

    // ---- epilogue: h = relu(acc + b1); logits = h @ W2 + b2; softmax; write
    float b1v[8], w2v[8][NCLS];
#pragma unroll
    for (int f = 0; f < 8; ++f) {
        int col = f * 16 + c0;
        b1v[f] = b1[col];
#pragma unroll
        for (int cc = 0; cc < NCLS; ++cc) w2v[f][cc] = W2[col * NCLS + cc];
    }
    float b2v[NCLS];
#pragma unroll
    for (int cc = 0; cc < NCLS; ++cc) b2v[cc] = b2[cc];

#pragma unroll
    for (int m = 0; m < 2; ++m) {
#pragma unroll
        for (int i = 0; i < 4; ++i) {
            float lg[NCLS] = {0.f, 0.f, 0.f, 0.f, 0.f};
#pragma unroll
            for (int f = 0; f < 8; ++f) {
                float h = acc[m][f][i] + b1v[f];
                h = fmaxf(h, 0.f);
#pragma unroll
                for (int cc = 0; cc < NCLS; ++cc) lg[cc] = fmaf(h, w2v[f][cc], lg[cc]);
            }
#pragma unroll
            for (int mask = 1; mask < 16; mask <<= 1) {
#pragma unroll
                for (int cc = 0; cc < NCLS; ++cc) lg[cc] += __shfl_xor(lg[cc], mask);
            }
#pragma unroll
            for (int cc = 0; cc < NCLS; ++cc) lg[cc] += b2v[cc];

            float mx = fmaxf(fmaxf(fmaxf(lg[0], lg[1]), fmaxf(lg[2], lg[3])), lg[4]);
            float q[NCLS];
            float s = 0.f;
#pragma unroll
            for (int cc = 0; cc < NCLS; ++cc) { q[cc] = __expf(lg[cc] - mx); s += q[cc]; }
            float inv = 1.0f / s;
            float num = (c0 == 0) ? q[0] : (c0 == 1) ? q[1] : (c0 == 2) ? q[2]
                      : (c0 == 3) ? q[3] : q[4];
            int rowl = wv * 32 + m * 16 + g * 4 + i;
            int eo = e0 + rowl;
            if (eo < E_TOT && c0 < NCLS) out[(size_t)eo * NCLS + c0] = num * inv;
        }
    }
}

extern "C" void kernel_launch(void* const* d_in, const int* in_sizes, int n_in,
                              void* d_out, int out_size, void* d_ws, size_t ws_size,
                              hipStream_t stream) {
    const float* z    = (const float*)d_in[0];
    const int*   ei   = (const int*)d_in[1];
    const float* attr = (const float*)d_in[2];
    const float* W1   = (const float*)d_in[3];
    const float* b1   = (const float*)d_in[4];
    const float* W2   = (const float*)d_in[5];
    const float* b2   = (const float*)d_in[6];
    float* out = (float*)d_out;
    __hip_bfloat16* w1f = (__hip_bfloat16*)d_ws;   // 26*8*64*8*2 = 212992 B

    prep_w1f<<<(26 * 8 * 64 * 8 + 255) / 256, 256, 0, stream>>>(W1, w1f);
    const int nblk = (E_TOT + 127) / 128;   // 1563
    gcn_main<<<nblk, 256, 0, stream>>>(z, ei, attr, w1f, b1, W2, b2, out);
}